// Round 9
// baseline (1773.953 us; speedup 1.0000x reference)
//
#include <hip/hip_runtime.h>
#include <stdint.h>

#define T_STEPS 1024
#define BATCH   512
#define INF     64
#define HID     128
#define OUTF    2

// d_out[0..1023] = z_sum [512][2], d_out[1024] = spikerate.
// During the seq kernel, d_out[1024] (reinterpreted as uint) is the global
// spike counter (exact integer atomics -> deterministic); finalize converts.

__global__ void zero_kernel(unsigned int* __restrict__ counter)
{
    *counter = 0u;
}

// grid 256 x 256 threads; block = 2 batch rows (g = tid>>7), neuron h = tid&127.
// Bit-exact semantics (verified absmax==0.0 in round 8):
//   - v,i state + elementwise: float64, np op order, no contraction
//   - inp = x@W_in.T, pre = inp@cWi.T : f32 seq-k single-acc FMA chains
//   - rec = z@Wrec.T : f64 sum — EXACT in any order (<=24-bit addends,
//     range <47 bits), so scheduling of rec is free
// Schedule (this round): 3-stream software pipeline, ONE barrier/step.
//   iter i: stage1->inp(i+2) || stage2->pre(i+1) (reg) || rec+LIF step i
//   x: 2-deep register-staged prefetch (load i+4, ds_write i+3)
__global__ __launch_bounds__(256, 1)
void snn_seq(const float* __restrict__ x,        // [T][B][64]
             const float* __restrict__ W_in,     // [128][64]
             const float* __restrict__ cWi,      // [128][128]
             const float* __restrict__ Wrec,     // [128][128]
             const float* __restrict__ W_out,    // [2][128]
             const float* __restrict__ b_out,    // [2]
             const float* __restrict__ v_th,     // [128]
             const float* __restrict__ v_leak1,  // [1]
             const float* __restrict__ v_reset,  // [128]
             const float* __restrict__ tau_mem,  // [128]
             const float* __restrict__ tau_syn,  // [128]
             float* __restrict__ out,            // [512][2] + [1]
             unsigned int* __restrict__ counter)
{
    #pragma clang fp contract(off)

    extern __shared__ char smem[];
    float* Wrec_T  = (float*)smem;                   // [128][128]
    float* x_lds   = Wrec_T + HID * HID;             // [2 buf][2 grp][64]
    float* inp_lds = x_lds + 2 * 2 * INF;            // [2 buf][2 grp][128]
    unsigned long long* mask_lds =
        (unsigned long long*)(inp_lds + 2 * 2 * HID); // [2 buf][2 grp][2 half]

    const int tid = threadIdx.x;
    const int g   = tid >> 7;
    const int h   = tid & (HID - 1);
    const int b   = blockIdx.x * 2 + g;
    const int wv  = (tid >> 6) & 1;
    const bool xload = (h < INF);

    for (int idx = tid; idx < HID * HID; idx += 256)
        Wrec_T[idx] = Wrec[(idx & (HID - 1)) * HID + (idx >> 7)];

    const double vth   = (double)v_th[h];
    const double vleak = (double)v_leak1[0];
    const double vrst  = (double)v_reset[h];
    const double dtm   = 0.001 * (double)tau_mem[h];
    const double dts   = 0.001 * (double)tau_syn[h];

    float win[INF];
    #pragma unroll
    for (int q = 0; q < INF / 4; ++q) {
        float4 w4 = ((const float4*)(W_in + h * INF))[q];
        win[4 * q + 0] = w4.x; win[4 * q + 1] = w4.y;
        win[4 * q + 2] = w4.z; win[4 * q + 3] = w4.w;
    }
    float cw[HID];
    #pragma unroll
    for (int q = 0; q < HID / 4; ++q) {
        float4 w4 = ((const float4*)(cWi + h * HID))[q];
        cw[4 * q + 0] = w4.x; cw[4 * q + 1] = w4.y;
        cw[4 * q + 2] = w4.z; cw[4 * q + 3] = w4.w;
    }

    if (tid < 8) mask_lds[tid] = 0ull;
    // ---- prologue staging: x(0)->xbuf0, x(1)->xbuf1
    if (xload) {
        x_lds[0 * 128 + g * 64 + h] = x[(size_t)(0 * BATCH + b) * INF + h];
        x_lds[1 * 128 + g * 64 + h] = x[(size_t)(1 * BATCH + b) * INF + h];
    }
    __syncthreads();

    // inp(0) -> inp_lds[0]
    {
        float s = 0.f;
        const float* xr = x_lds + 0 * 128 + g * 64;
        #pragma unroll
        for (int k = 0; k < INF; k += 4) {
            float4 x4 = *(const float4*)(xr + k);
            s = fmaf(x4.x, win[k + 0], s);
            s = fmaf(x4.y, win[k + 1], s);
            s = fmaf(x4.z, win[k + 2], s);
            s = fmaf(x4.w, win[k + 3], s);
        }
        inp_lds[0 * 256 + g * 128 + h] = s;
    }
    __syncthreads();

    // pre(0) -> pre_reg ; inp(1) -> inp_lds[1] ; x(2)->xbuf0 ; xnext = x(3)
    float pre_reg;
    {
        float p = 0.f;
        const float* ir = inp_lds + 0 * 256 + g * 128;
        #pragma unroll
        for (int j = 0; j < HID; j += 4) {
            float4 i4 = *(const float4*)(ir + j);
            p = fmaf(i4.x, cw[j + 0], p);
            p = fmaf(i4.y, cw[j + 1], p);
            p = fmaf(i4.z, cw[j + 2], p);
            p = fmaf(i4.w, cw[j + 3], p);
        }
        pre_reg = p;
    }
    {
        float s = 0.f;
        const float* xr = x_lds + 1 * 128 + g * 64;
        #pragma unroll
        for (int k = 0; k < INF; k += 4) {
            float4 x4 = *(const float4*)(xr + k);
            s = fmaf(x4.x, win[k + 0], s);
            s = fmaf(x4.y, win[k + 1], s);
            s = fmaf(x4.z, win[k + 2], s);
            s = fmaf(x4.w, win[k + 3], s);
        }
        inp_lds[1 * 256 + g * 128 + h] = s;
    }
    float xnext = 0.f;
    if (xload) {
        x_lds[0 * 128 + g * 64 + h] = x[(size_t)(2 * BATCH + b) * INF + h];
        xnext = x[(size_t)(3 * BATCH + b) * INF + h];
    }
    __syncthreads();

    double v = 0.0, cur = 0.0;
    int cnt = 0;

    for (int i = 0; i < T_STEPS; ++i) {
        const int buf  = i & 1;
        const int nbuf = buf ^ 1;

        // ---- x handoff: ds_write x(i+3), issue load x(i+4) (earliest point)
        if (xload) {
            x_lds[nbuf * 128 + g * 64 + h] = xnext;
            int tn = (i + 4 < T_STEPS) ? i + 4 : T_STEPS - 1;
            xnext = x[((size_t)tn * BATCH + b) * INF + h];
        }

        // ---- masks (z(i-1)) for this row
        unsigned long long m0 = mask_lds[buf * 4 + g * 2 + 0];
        unsigned long long m1 = mask_lds[buf * 4 + g * 2 + 1];

        // ---- stream A: stage1 inp(i+2) from xbuf[buf]
        float sW = 0.f;
        {
            const float* xr = x_lds + buf * 128 + g * 64;
            #pragma unroll
            for (int k = 0; k < INF; k += 4) {
                float4 x4 = *(const float4*)(xr + k);
                sW = fmaf(x4.x, win[k + 0], sW);
                sW = fmaf(x4.y, win[k + 1], sW);
                sW = fmaf(x4.z, win[k + 2], sW);
                sW = fmaf(x4.w, win[k + 3], sW);
            }
        }
        inp_lds[buf * 256 + g * 128 + h] = sW;

        // ---- stream B: stage2 pre(i+1) from inp_lds[nbuf] -> register
        float pre_next = 0.f;
        {
            const float* ir = inp_lds + nbuf * 256 + g * 128;
            #pragma unroll
            for (int j = 0; j < HID; j += 4) {
                float4 i4 = *(const float4*)(ir + j);
                pre_next = fmaf(i4.x, cw[j + 0], pre_next);
                pre_next = fmaf(i4.y, cw[j + 1], pre_next);
                pre_next = fmaf(i4.z, cw[j + 2], pre_next);
                pre_next = fmaf(i4.w, cw[j + 3], pre_next);
            }
        }

        // ---- stream C: rec (exact f64 sum, order-free) — lockstep 4-chain
        double r0 = 0.0, r1 = 0.0, r2 = 0.0, r3 = 0.0;
        {
            uint32_t c0 = (uint32_t)m0, c1 = (uint32_t)(m0 >> 32);
            uint32_t c2 = (uint32_t)m1, c3 = (uint32_t)(m1 >> 32);
            while (c0 | c1 | c2 | c3) {
                float w0 = 0.f, w1 = 0.f, w2 = 0.f, w3 = 0.f;
                if (c0) { int j = __builtin_ctz(c0); c0 &= c0 - 1; w0 = Wrec_T[j * HID + h]; }
                if (c1) { int j = __builtin_ctz(c1); c1 &= c1 - 1; w1 = Wrec_T[(j + 32) * HID + h]; }
                if (c2) { int j = __builtin_ctz(c2); c2 &= c2 - 1; w2 = Wrec_T[(j + 64) * HID + h]; }
                if (c3) { int j = __builtin_ctz(c3); c3 &= c3 - 1; w3 = Wrec_T[(j + 96) * HID + h]; }
                r0 += (double)w0; r1 += (double)w1;
                r2 += (double)w2; r3 += (double)w3;
            }
        }
        double rec = (r0 + r1) + (r2 + r3);

        // ---- LIF step i: float64, np op order
        double v_dec = v + dtm * ((vleak - v) + cur);
        double i_dec = cur - dts * cur;
        bool   z     = (v_dec - vth) > 0.0;
        v   = z ? vrst : v_dec;
        cur = (i_dec + (double)pre_reg) + rec;
        cnt += z ? 1 : 0;

        unsigned long long bal = __ballot(z);
        if ((tid & 63) == 0) mask_lds[nbuf * 4 + g * 2 + wv] = bal;

        pre_reg = pre_next;
        __syncthreads();
    }

    // ---- epilogue: z_sum[b] = (sum_t z)@W_out.T + T*b_out ; spike count
    float* cnt_lds = inp_lds;          // reuse
    cnt_lds[tid] = (float)cnt;         // counts <= 1024: exact
    __syncthreads();
    if (tid < 4) {
        int go = tid >> 1, oo = tid & 1;
        double sAcc = 0.0;
        for (int hh = 0; hh < HID; ++hh)
            sAcc += (double)cnt_lds[go * HID + hh] * (double)W_out[oo * HID + hh];
        out[(size_t)(blockIdx.x * 2 + go) * OUTF + oo] =
            (float)(sAcc + 1024.0 * (double)b_out[oo]);
    }
    if (tid == 0) {
        unsigned int tot = 0;
        for (int k2 = 0; k2 < 256; ++k2) tot += (unsigned int)cnt_lds[k2];
        atomicAdd(counter, tot);
    }
}

__global__ void finalize_kernel(float* __restrict__ out)
{
    unsigned int c = ((const unsigned int*)out)[BATCH * OUTF];
    out[BATCH * OUTF] = (float)c * 0x1p-26f;   // / (1024*512*128), exact pow2
}

extern "C" void kernel_launch(void* const* d_in, const int* in_sizes, int n_in,
                              void* d_out, int out_size, void* d_ws, size_t ws_size,
                              hipStream_t stream) {
    (void)in_sizes; (void)n_in; (void)d_ws; (void)ws_size; (void)out_size;

    const float* x       = (const float*)d_in[0];
    const float* W_in    = (const float*)d_in[1];
    const float* cWi     = (const float*)d_in[2];
    const float* cWr     = (const float*)d_in[3];
    const float* W_out   = (const float*)d_in[4];
    const float* b_out   = (const float*)d_in[5];
    // d_in[6] = alpha (unused in forward)
    const float* v_th    = (const float*)d_in[7];
    const float* v_leak  = (const float*)d_in[8];
    const float* v_reset = (const float*)d_in[9];
    const float* tau_mem = (const float*)d_in[10];
    const float* tau_syn = (const float*)d_in[11];
    float* out = (float*)d_out;
    unsigned int* counter = (unsigned int*)out + BATCH * OUTF;

    zero_kernel<<<1, 1, 0, stream>>>(counter);

    const size_t lds_bytes =
        (size_t)(HID * HID + 2 * 2 * INF + 2 * 2 * HID) * sizeof(float)
        + 2 * 2 * 2 * sizeof(unsigned long long);
    snn_seq<<<dim3(256), dim3(256), lds_bytes, stream>>>(
        x, W_in, cWi, cWr, W_out, b_out, v_th, v_leak, v_reset,
        tau_mem, tau_syn, out, counter);

    finalize_kernel<<<1, 1, 0, stream>>>(out);
}

// Round 10
// 1043.402 us; speedup vs baseline: 1.7002x; 1.7002x over previous
//
#include <hip/hip_runtime.h>
#include <stdint.h>

#define T_STEPS 1024
#define BATCH   512
#define INF     64
#define HID     128
#define OUTF    2

// d_out[0..1023] = z_sum [512][2], d_out[1024] = spikerate.
// During the seq kernel, d_out[1024] (reinterpreted as uint) is the global
// spike counter (exact integer atomics -> deterministic); finalize converts.

__global__ void zero_kernel(unsigned int* __restrict__ counter)
{
    *counter = 0u;
}

// grid 256 x 512 threads; block = 2 batch rows.
// WAVE SPECIALIZATION: tid<256 = input waves (stage1+stage2 pipeline),
// tid>=256 = recurrence waves (rec scan + LIF + masks). 2 waves/SIMD.
// Bit-exact semantics (verified absmax==0.0 rounds 8/9):
//   - v,i state + elementwise: float64, np op order, no contraction
//   - inp = x@W_in.T, pre = inp@cWi.T : f32 seq-k single-acc FMA chains
//   - rec = z@Wrec.T : f64 sum — exact in any order
// Pipeline (unchanged from round 9): iter i computes inp(i+2), pre(i+1),
// consumes pre(i); x register-staged 2 deep. One barrier per step.
__global__ __launch_bounds__(512, 2)
void snn_seq(const float* __restrict__ x,        // [T][B][64]
             const float* __restrict__ W_in,     // [128][64]
             const float* __restrict__ cWi,      // [128][128]
             const float* __restrict__ Wrec,     // [128][128]
             const float* __restrict__ W_out,    // [2][128]
             const float* __restrict__ b_out,    // [2]
             const float* __restrict__ v_th,     // [128]
             const float* __restrict__ v_leak1,  // [1]
             const float* __restrict__ v_reset,  // [128]
             const float* __restrict__ tau_mem,  // [128]
             const float* __restrict__ tau_syn,  // [128]
             float* __restrict__ out,            // [512][2] + [1]
             unsigned int* __restrict__ counter)
{
    #pragma clang fp contract(off)

    extern __shared__ char smem[];
    float* Wrec_T  = (float*)smem;                    // [128][128]
    float* x_lds   = Wrec_T + HID * HID;              // [2 buf][2 grp][64]
    float* inp_lds = x_lds + 2 * 2 * INF;             // [2 buf][2 grp][128]
    float* pre_lds = inp_lds + 2 * 2 * HID;           // [2 buf][2 grp][128]
    unsigned long long* mask_lds =
        (unsigned long long*)(pre_lds + 2 * 2 * HID); // [2 buf][2 grp][2 half]

    const int  tid    = threadIdx.x;
    const bool is_inp = (tid < 256);
    const int  rt     = tid & 255;          // role-local tid
    const int  g      = rt >> 7;            // batch row within block
    const int  h      = rt & (HID - 1);     // neuron index
    const int  b      = blockIdx.x * 2 + g;
    const int  wv     = (rt >> 6) & 1;      // wave half within group

    for (int idx = tid; idx < HID * HID; idx += 512)
        Wrec_T[idx] = Wrec[(idx & (HID - 1)) * HID + (idx >> 7)];

    if (tid < 8) mask_lds[tid] = 0ull;

    // ---- role-specific setup
    float win[INF];
    float cw[HID];
    double vth = 0.0, vleak = 0.0, vrst = 0.0, dtm = 0.0, dts = 0.0;
    float xnext = 0.f;
    if (is_inp) {
        #pragma unroll
        for (int q = 0; q < INF / 4; ++q) {
            float4 w4 = ((const float4*)(W_in + h * INF))[q];
            win[4 * q + 0] = w4.x; win[4 * q + 1] = w4.y;
            win[4 * q + 2] = w4.z; win[4 * q + 3] = w4.w;
        }
        #pragma unroll
        for (int q = 0; q < HID / 4; ++q) {
            float4 w4 = ((const float4*)(cWi + h * HID))[q];
            cw[4 * q + 0] = w4.x; cw[4 * q + 1] = w4.y;
            cw[4 * q + 2] = w4.z; cw[4 * q + 3] = w4.w;
        }
        if (h < INF) {
            x_lds[0 * 128 + g * 64 + h] = x[(size_t)(0 * BATCH + b) * INF + h];
            x_lds[1 * 128 + g * 64 + h] = x[(size_t)(1 * BATCH + b) * INF + h];
        }
    } else {
        vth   = (double)v_th[h];
        vleak = (double)v_leak1[0];
        vrst  = (double)v_reset[h];
        dtm   = 0.001 * (double)tau_mem[h];
        dts   = 0.001 * (double)tau_syn[h];
    }
    __syncthreads();

    // ---- prologue: inp(0) -> inp_lds[0]
    if (is_inp) {
        float s = 0.f;
        const float* xr = x_lds + 0 * 128 + g * 64;
        #pragma unroll
        for (int k = 0; k < INF; k += 4) {
            float4 x4 = *(const float4*)(xr + k);
            s = fmaf(x4.x, win[k + 0], s);
            s = fmaf(x4.y, win[k + 1], s);
            s = fmaf(x4.z, win[k + 2], s);
            s = fmaf(x4.w, win[k + 3], s);
        }
        inp_lds[0 * 256 + g * 128 + h] = s;
    }
    __syncthreads();

    // ---- prologue: pre(0)->pre_lds[0], inp(1)->inp_lds[1], x(2)->xbuf0, xnext=x(3)
    if (is_inp) {
        float p = 0.f;
        const float* ir = inp_lds + 0 * 256 + g * 128;
        #pragma unroll
        for (int j = 0; j < HID; j += 4) {
            float4 i4 = *(const float4*)(ir + j);
            p = fmaf(i4.x, cw[j + 0], p);
            p = fmaf(i4.y, cw[j + 1], p);
            p = fmaf(i4.z, cw[j + 2], p);
            p = fmaf(i4.w, cw[j + 3], p);
        }
        pre_lds[0 * 256 + g * 128 + h] = p;

        float s = 0.f;
        const float* xr = x_lds + 1 * 128 + g * 64;
        #pragma unroll
        for (int k = 0; k < INF; k += 4) {
            float4 x4 = *(const float4*)(xr + k);
            s = fmaf(x4.x, win[k + 0], s);
            s = fmaf(x4.y, win[k + 1], s);
            s = fmaf(x4.z, win[k + 2], s);
            s = fmaf(x4.w, win[k + 3], s);
        }
        inp_lds[1 * 256 + g * 128 + h] = s;

        if (h < INF) {
            x_lds[0 * 128 + g * 64 + h] = x[(size_t)(2 * BATCH + b) * INF + h];
            xnext = x[(size_t)(3 * BATCH + b) * INF + h];
        }
    }
    __syncthreads();

    double v = 0.0, cur = 0.0;
    int cnt = 0;

    for (int i = 0; i < T_STEPS; ++i) {
        const int buf  = i & 1;
        const int nbuf = buf ^ 1;

        if (is_inp) {
            // x handoff: ds_write x(i+3), issue load x(i+4)
            if (h < INF) {
                x_lds[nbuf * 128 + g * 64 + h] = xnext;
                int tn = (i + 4 < T_STEPS) ? i + 4 : T_STEPS - 1;
                xnext = x[((size_t)tn * BATCH + b) * INF + h];
            }
            // stage1: inp(i+2) from xbuf[buf]
            float sW = 0.f;
            {
                const float* xr = x_lds + buf * 128 + g * 64;
                #pragma unroll
                for (int k = 0; k < INF; k += 4) {
                    float4 x4 = *(const float4*)(xr + k);
                    sW = fmaf(x4.x, win[k + 0], sW);
                    sW = fmaf(x4.y, win[k + 1], sW);
                    sW = fmaf(x4.z, win[k + 2], sW);
                    sW = fmaf(x4.w, win[k + 3], sW);
                }
            }
            inp_lds[buf * 256 + g * 128 + h] = sW;
            // stage2: pre(i+1) from inp_lds[nbuf] -> pre_lds[nbuf]
            float p = 0.f;
            {
                const float* ir = inp_lds + nbuf * 256 + g * 128;
                #pragma unroll
                for (int j = 0; j < HID; j += 4) {
                    float4 i4 = *(const float4*)(ir + j);
                    p = fmaf(i4.x, cw[j + 0], p);
                    p = fmaf(i4.y, cw[j + 1], p);
                    p = fmaf(i4.z, cw[j + 2], p);
                    p = fmaf(i4.w, cw[j + 3], p);
                }
            }
            pre_lds[nbuf * 256 + g * 128 + h] = p;
        } else {
            // recurrence: rec (exact f64, order-free) + LIF step i
            unsigned long long m0 = mask_lds[buf * 4 + g * 2 + 0];
            unsigned long long m1 = mask_lds[buf * 4 + g * 2 + 1];
            float pre32 = pre_lds[buf * 256 + g * 128 + h];

            double r0 = 0.0, r1 = 0.0, r2 = 0.0, r3 = 0.0;
            {
                uint32_t c0 = (uint32_t)m0, c1 = (uint32_t)(m0 >> 32);
                uint32_t c2 = (uint32_t)m1, c3 = (uint32_t)(m1 >> 32);
                while (c0 | c1 | c2 | c3) {
                    float w0 = 0.f, w1 = 0.f, w2 = 0.f, w3 = 0.f;
                    if (c0) { int j = __builtin_ctz(c0); c0 &= c0 - 1; w0 = Wrec_T[j * HID + h]; }
                    if (c1) { int j = __builtin_ctz(c1); c1 &= c1 - 1; w1 = Wrec_T[(j + 32) * HID + h]; }
                    if (c2) { int j = __builtin_ctz(c2); c2 &= c2 - 1; w2 = Wrec_T[(j + 64) * HID + h]; }
                    if (c3) { int j = __builtin_ctz(c3); c3 &= c3 - 1; w3 = Wrec_T[(j + 96) * HID + h]; }
                    r0 += (double)w0; r1 += (double)w1;
                    r2 += (double)w2; r3 += (double)w3;
                }
            }
            double rec = (r0 + r1) + (r2 + r3);

            double v_dec = v + dtm * ((vleak - v) + cur);
            double i_dec = cur - dts * cur;
            bool   z     = (v_dec - vth) > 0.0;
            v   = z ? vrst : v_dec;
            cur = (i_dec + (double)pre32) + rec;
            cnt += z ? 1 : 0;

            unsigned long long bal = __ballot(z);
            if ((rt & 63) == 0) mask_lds[nbuf * 4 + g * 2 + wv] = bal;
        }
        __syncthreads();
    }

    // ---- epilogue: z_sum[b] = (sum_t z)@W_out.T + T*b_out ; spike count
    float* cnt_lds = inp_lds;              // reuse (512 floats; use first 256)
    if (!is_inp) cnt_lds[g * 128 + h] = (float)cnt;   // counts <= 1024: exact
    __syncthreads();
    if (tid < 4) {
        int go = tid >> 1, oo = tid & 1;
        double sAcc = 0.0;
        for (int hh = 0; hh < HID; ++hh)
            sAcc += (double)cnt_lds[go * HID + hh] * (double)W_out[oo * HID + hh];
        out[(size_t)(blockIdx.x * 2 + go) * OUTF + oo] =
            (float)(sAcc + 1024.0 * (double)b_out[oo]);
    }
    if (tid == 0) {
        unsigned int tot = 0;
        for (int k2 = 0; k2 < 256; ++k2) tot += (unsigned int)cnt_lds[k2];
        atomicAdd(counter, tot);
    }
}

__global__ void finalize_kernel(float* __restrict__ out)
{
    unsigned int c = ((const unsigned int*)out)[BATCH * OUTF];
    out[BATCH * OUTF] = (float)c * 0x1p-26f;   // / (1024*512*128), exact pow2
}

extern "C" void kernel_launch(void* const* d_in, const int* in_sizes, int n_in,
                              void* d_out, int out_size, void* d_ws, size_t ws_size,
                              hipStream_t stream) {
    (void)in_sizes; (void)n_in; (void)d_ws; (void)ws_size; (void)out_size;

    const float* x       = (const float*)d_in[0];
    const float* W_in    = (const float*)d_in[1];
    const float* cWi     = (const float*)d_in[2];
    const float* cWr     = (const float*)d_in[3];
    const float* W_out   = (const float*)d_in[4];
    const float* b_out   = (const float*)d_in[5];
    // d_in[6] = alpha (unused in forward)
    const float* v_th    = (const float*)d_in[7];
    const float* v_leak  = (const float*)d_in[8];
    const float* v_reset = (const float*)d_in[9];
    const float* tau_mem = (const float*)d_in[10];
    const float* tau_syn = (const float*)d_in[11];
    float* out = (float*)d_out;
    unsigned int* counter = (unsigned int*)out + BATCH * OUTF;

    zero_kernel<<<1, 1, 0, stream>>>(counter);

    const size_t lds_bytes =
        (size_t)(HID * HID + 2 * 2 * INF + 2 * 2 * HID + 2 * 2 * HID) * sizeof(float)
        + 2 * 2 * 2 * sizeof(unsigned long long);
    snn_seq<<<dim3(256), dim3(512), lds_bytes, stream>>>(
        x, W_in, cWi, cWr, W_out, b_out, v_th, v_leak, v_reset,
        tau_mem, tau_syn, out, counter);

    finalize_kernel<<<1, 1, 0, stream>>>(out);
}

// Round 11
// 1039.742 us; speedup vs baseline: 1.7061x; 1.0035x over previous
//
#include <hip/hip_runtime.h>
#include <stdint.h>

#define T_STEPS 1024
#define BATCH   512
#define INF     64
#define HID     128
#define OUTF    2

// d_out[0..1023] = z_sum [512][2], d_out[1024] = spikerate.
// During the seq kernel, d_out[1024] (reinterpreted as uint) is the global
// spike counter (exact integer atomics -> deterministic); finalize converts.

__global__ void zero_kernel(unsigned int* __restrict__ counter)
{
    *counter = 0u;
}

// grid 512 x 256 threads; block = ONE batch row b = blockIdx.x.
// Roles: tid<128 = input waves (stage1+stage2), tid>=128 = recurrence waves.
// 4 waves/block, 66.5 KB LDS -> 2 blocks/CU = two independent barrier domains.
// In-loop barrier: lgkmcnt(0)+s_barrier ONLY (no vmcnt drain) so the x
// global prefetch stays in flight across barriers (first use = ds_write one
// full iteration later -> HBM latency fully hidden).
// Bit-exact semantics (verified absmax==0.0 rounds 8-10):
//   - v,i state + elementwise: float64, np op order, no contraction
//   - inp = x@W_in.T, pre = inp@cWi.T : f32 seq-k single-acc FMA chains
//   - rec = z@Wrec.T : f64 sum — exact in any order
// Pipeline: iter i computes inp(i+2), pre(i+1), consumes pre(i);
// x register-staged (load i+4, ds_write i+3). One barrier per step.
__global__ __launch_bounds__(256, 2)
void snn_seq(const float* __restrict__ x,        // [T][B][64]
             const float* __restrict__ W_in,     // [128][64]
             const float* __restrict__ cWi,      // [128][128]
             const float* __restrict__ Wrec,     // [128][128]
             const float* __restrict__ W_out,    // [2][128]
             const float* __restrict__ b_out,    // [2]
             const float* __restrict__ v_th,     // [128]
             const float* __restrict__ v_leak1,  // [1]
             const float* __restrict__ v_reset,  // [128]
             const float* __restrict__ tau_mem,  // [128]
             const float* __restrict__ tau_syn,  // [128]
             float* __restrict__ out,            // [512][2] + [1]
             unsigned int* __restrict__ counter)
{
    #pragma clang fp contract(off)

    extern __shared__ char smem[];
    float* Wrec_T  = (float*)smem;                 // [128][128]
    float* x_lds   = Wrec_T + HID * HID;           // [2 buf][64]
    float* inp_lds = x_lds + 2 * INF;              // [2 buf][128]
    float* pre_lds = inp_lds + 2 * HID;            // [2 buf][128]
    unsigned long long* mask_lds =
        (unsigned long long*)(pre_lds + 2 * HID);  // [2 buf][2 half]

    const int  tid    = threadIdx.x;
    const bool is_inp = (tid < 128);
    const int  h      = tid & (HID - 1);
    const int  b      = blockIdx.x;
    const int  rt     = tid - 128;                 // rec-role local tid

    for (int idx = tid; idx < HID * HID; idx += 256)
        Wrec_T[idx] = Wrec[(idx & (HID - 1)) * HID + (idx >> 7)];

    if (tid < 4) mask_lds[tid] = 0ull;

    // ---- role-specific setup
    float win[INF];
    float cw[HID];
    double vth = 0.0, vleak = 0.0, vrst = 0.0, dtm = 0.0, dts = 0.0;
    float xnext = 0.f;
    if (is_inp) {
        #pragma unroll
        for (int q = 0; q < INF / 4; ++q) {
            float4 w4 = ((const float4*)(W_in + h * INF))[q];
            win[4 * q + 0] = w4.x; win[4 * q + 1] = w4.y;
            win[4 * q + 2] = w4.z; win[4 * q + 3] = w4.w;
        }
        #pragma unroll
        for (int q = 0; q < HID / 4; ++q) {
            float4 w4 = ((const float4*)(cWi + h * HID))[q];
            cw[4 * q + 0] = w4.x; cw[4 * q + 1] = w4.y;
            cw[4 * q + 2] = w4.z; cw[4 * q + 3] = w4.w;
        }
        if (h < INF) {
            x_lds[0 * INF + h] = x[(size_t)(0 * BATCH + b) * INF + h];
            x_lds[1 * INF + h] = x[(size_t)(1 * BATCH + b) * INF + h];
        }
    } else {
        vth   = (double)v_th[h];
        vleak = (double)v_leak1[0];
        vrst  = (double)v_reset[h];
        dtm   = 0.001 * (double)tau_mem[h];
        dts   = 0.001 * (double)tau_syn[h];
    }
    __syncthreads();

    // ---- prologue: inp(0) -> inp_lds[0]
    if (is_inp) {
        float s = 0.f;
        const float* xr = x_lds + 0 * INF;
        #pragma unroll
        for (int k = 0; k < INF; k += 4) {
            float4 x4 = *(const float4*)(xr + k);
            s = fmaf(x4.x, win[k + 0], s);
            s = fmaf(x4.y, win[k + 1], s);
            s = fmaf(x4.z, win[k + 2], s);
            s = fmaf(x4.w, win[k + 3], s);
        }
        inp_lds[0 * HID + h] = s;
    }
    __syncthreads();

    // ---- prologue: pre(0)->pre_lds[0], inp(1)->inp_lds[1], x(2)->xbuf0, xnext=x(3)
    if (is_inp) {
        float p = 0.f;
        const float* ir = inp_lds + 0 * HID;
        #pragma unroll
        for (int j = 0; j < HID; j += 4) {
            float4 i4 = *(const float4*)(ir + j);
            p = fmaf(i4.x, cw[j + 0], p);
            p = fmaf(i4.y, cw[j + 1], p);
            p = fmaf(i4.z, cw[j + 2], p);
            p = fmaf(i4.w, cw[j + 3], p);
        }
        pre_lds[0 * HID + h] = p;

        float s = 0.f;
        const float* xr = x_lds + 1 * INF;
        #pragma unroll
        for (int k = 0; k < INF; k += 4) {
            float4 x4 = *(const float4*)(xr + k);
            s = fmaf(x4.x, win[k + 0], s);
            s = fmaf(x4.y, win[k + 1], s);
            s = fmaf(x4.z, win[k + 2], s);
            s = fmaf(x4.w, win[k + 3], s);
        }
        inp_lds[1 * HID + h] = s;

        if (h < INF) {
            x_lds[0 * INF + h] = x[(size_t)(2 * BATCH + b) * INF + h];
            xnext = x[(size_t)(3 * BATCH + b) * INF + h];
        }
    }
    __syncthreads();

    double v = 0.0, cur = 0.0;
    int cnt = 0;

    for (int i = 0; i < T_STEPS; ++i) {
        const int buf  = i & 1;
        const int nbuf = buf ^ 1;

        if (is_inp) {
            // x handoff: ds_write x(i+3), issue load x(i+4) (stays in flight
            // across the barrier; vmcnt-waited only at next iter's ds_write)
            if (h < INF) {
                x_lds[nbuf * INF + h] = xnext;
                int tn = (i + 4 < T_STEPS) ? i + 4 : T_STEPS - 1;
                xnext = x[((size_t)tn * BATCH + b) * INF + h];
            }
            // stage1: inp(i+2) from xbuf[buf]
            float sW = 0.f;
            {
                const float* xr = x_lds + buf * INF;
                #pragma unroll
                for (int k = 0; k < INF; k += 4) {
                    float4 x4 = *(const float4*)(xr + k);
                    sW = fmaf(x4.x, win[k + 0], sW);
                    sW = fmaf(x4.y, win[k + 1], sW);
                    sW = fmaf(x4.z, win[k + 2], sW);
                    sW = fmaf(x4.w, win[k + 3], sW);
                }
            }
            inp_lds[buf * HID + h] = sW;
            // stage2: pre(i+1) from inp_lds[nbuf] -> pre_lds[nbuf]
            float p = 0.f;
            {
                const float* ir = inp_lds + nbuf * HID;
                #pragma unroll
                for (int j = 0; j < HID; j += 4) {
                    float4 i4 = *(const float4*)(ir + j);
                    p = fmaf(i4.x, cw[j + 0], p);
                    p = fmaf(i4.y, cw[j + 1], p);
                    p = fmaf(i4.z, cw[j + 2], p);
                    p = fmaf(i4.w, cw[j + 3], p);
                }
            }
            pre_lds[nbuf * HID + h] = p;
        } else {
            // recurrence: rec (exact f64, order-free) + LIF step i
            unsigned long long m0 = mask_lds[buf * 2 + 0];
            unsigned long long m1 = mask_lds[buf * 2 + 1];
            float pre32 = pre_lds[buf * HID + h];

            double r0 = 0.0, r1 = 0.0, r2 = 0.0, r3 = 0.0;
            {
                uint32_t c0 = (uint32_t)m0, c1 = (uint32_t)(m0 >> 32);
                uint32_t c2 = (uint32_t)m1, c3 = (uint32_t)(m1 >> 32);
                while (c0 | c1 | c2 | c3) {
                    float w0 = 0.f, w1 = 0.f, w2 = 0.f, w3 = 0.f;
                    if (c0) { int j = __builtin_ctz(c0); c0 &= c0 - 1; w0 = Wrec_T[j * HID + h]; }
                    if (c1) { int j = __builtin_ctz(c1); c1 &= c1 - 1; w1 = Wrec_T[(j + 32) * HID + h]; }
                    if (c2) { int j = __builtin_ctz(c2); c2 &= c2 - 1; w2 = Wrec_T[(j + 64) * HID + h]; }
                    if (c3) { int j = __builtin_ctz(c3); c3 &= c3 - 1; w3 = Wrec_T[(j + 96) * HID + h]; }
                    r0 += (double)w0; r1 += (double)w1;
                    r2 += (double)w2; r3 += (double)w3;
                }
            }
            double rec = (r0 + r1) + (r2 + r3);

            double v_dec = v + dtm * ((vleak - v) + cur);
            double i_dec = cur - dts * cur;
            bool   z     = (v_dec - vth) > 0.0;
            v   = z ? vrst : v_dec;
            cur = (i_dec + (double)pre32) + rec;
            cnt += z ? 1 : 0;

            unsigned long long bal = __ballot(z);
            if ((rt & 63) == 0) mask_lds[nbuf * 2 + (rt >> 6)] = bal;
        }
        // barrier WITHOUT vmcnt drain: LDS ordering only
        asm volatile("s_waitcnt lgkmcnt(0)\n\ts_barrier" ::: "memory");
    }

    // ---- epilogue: z_sum[b] = (sum_t z)@W_out.T + T*b_out ; spike count
    float* cnt_lds = pre_lds;            // reuse (first 128 floats)
    if (!is_inp) cnt_lds[h] = (float)cnt;   // counts <= 1024: exact
    __syncthreads();
    if (tid < OUTF) {
        double sAcc = 0.0;
        for (int hh = 0; hh < HID; ++hh)
            sAcc += (double)cnt_lds[hh] * (double)W_out[tid * HID + hh];
        out[(size_t)b * OUTF + tid] = (float)(sAcc + 1024.0 * (double)b_out[tid]);
    }
    if (tid == 0) {
        unsigned int tot = 0;
        for (int k2 = 0; k2 < HID; ++k2) tot += (unsigned int)cnt_lds[k2];
        atomicAdd(counter, tot);
    }
}

__global__ void finalize_kernel(float* __restrict__ out)
{
    unsigned int c = ((const unsigned int*)out)[BATCH * OUTF];
    out[BATCH * OUTF] = (float)c * 0x1p-26f;   // / (1024*512*128), exact pow2
}

extern "C" void kernel_launch(void* const* d_in, const int* in_sizes, int n_in,
                              void* d_out, int out_size, void* d_ws, size_t ws_size,
                              hipStream_t stream) {
    (void)in_sizes; (void)n_in; (void)d_ws; (void)ws_size; (void)out_size;

    const float* x       = (const float*)d_in[0];
    const float* W_in    = (const float*)d_in[1];
    const float* cWi     = (const float*)d_in[2];
    const float* cWr     = (const float*)d_in[3];
    const float* W_out   = (const float*)d_in[4];
    const float* b_out   = (const float*)d_in[5];
    // d_in[6] = alpha (unused in forward)
    const float* v_th    = (const float*)d_in[7];
    const float* v_leak  = (const float*)d_in[8];
    const float* v_reset = (const float*)d_in[9];
    const float* tau_mem = (const float*)d_in[10];
    const float* tau_syn = (const float*)d_in[11];
    float* out = (float*)d_out;
    unsigned int* counter = (unsigned int*)out + BATCH * OUTF;

    zero_kernel<<<1, 1, 0, stream>>>(counter);

    const size_t lds_bytes =
        (size_t)(HID * HID + 2 * INF + 2 * HID + 2 * HID) * sizeof(float)
        + 2 * 2 * sizeof(unsigned long long);
    snn_seq<<<dim3(512), dim3(256), lds_bytes, stream>>>(
        x, W_in, cWi, cWr, W_out, b_out, v_th, v_leak, v_reset,
        tau_mem, tau_syn, out, counter);

    finalize_kernel<<<1, 1, 0, stream>>>(out);
}

// Round 12
// 733.636 us; speedup vs baseline: 2.4180x; 1.4172x over previous
//
#include <hip/hip_runtime.h>
#include <stdint.h>

#define T_STEPS 1024
#define BATCH   512
#define INF     64
#define HID     128
#define OUTF    2

// d_out[0..1023] = z_sum [512][2], d_out[1024] = spikerate.
__global__ void zero_kernel(unsigned int* __restrict__ counter)
{
    *counter = 0u;
}

#define FOR16(M) M(0)M(1)M(2)M(3)M(4)M(5)M(6)M(7)M(8)M(9)M(10)M(11)M(12)M(13)M(14)M(15)
#define FOR32(M) FOR16(M) M(16)M(17)M(18)M(19)M(20)M(21)M(22)M(23)M(24)M(25)M(26)M(27)M(28)M(29)M(30)M(31)

#define BARRIER() asm volatile("s_waitcnt lgkmcnt(0)\n\ts_barrier" ::: "memory")

// grid 512 x 256 threads; block = ONE batch row b = blockIdx.x. 66.5KB LDS -> 2 blocks/CU.
// Roles (wave-aligned):
//   tid   0..127 : stage2 waves  — pre(i+1) = inp(i+1)@cWi.T   (cw row in 32 named float4)
//   tid 128..191 : stage1 wave   — inp(i+2) = x(i+2)@W_in.T, 2 outputs/lane; x prefetch
//   tid 192..255 : rec wave      — 2 neurons/lane (h=2l,2l+1); masks in-register via
//                  2 ballots; batched b64 scan of Wrec_T; LIF; NO LDS writes.
// Bit-exact semantics (verified absmax==0.0 rounds 8-11):
//   - v,i state + elementwise: float64, np op order, no contraction
//   - inp/pre: f32 seq-k single-accumulator FMA chains (class-A)
//   - rec: f64 sum of f32 weights — exact in any order
__global__ __launch_bounds__(256) __attribute__((amdgpu_waves_per_eu(2, 2)))
void snn_seq(const float* __restrict__ x,        // [T][B][64]
             const float* __restrict__ W_in,     // [128][64]
             const float* __restrict__ cWi,      // [128][128]
             const float* __restrict__ Wrec,     // [128][128]
             const float* __restrict__ W_out,    // [2][128]
             const float* __restrict__ b_out,    // [2]
             const float* __restrict__ v_th,     // [128]
             const float* __restrict__ v_leak1,  // [1]
             const float* __restrict__ v_reset,  // [128]
             const float* __restrict__ tau_mem,  // [128]
             const float* __restrict__ tau_syn,  // [128]
             float* __restrict__ out,            // [512][2] + [1]
             unsigned int* __restrict__ counter)
{
    #pragma clang fp contract(off)

    extern __shared__ char smem[];
    float* Wrec_T  = (float*)smem;                 // [128][128]: Wrec_T[j][h] = Wrec[h][j]
    float* x_lds   = Wrec_T + HID * HID;           // [2 buf][64]
    float* inp_lds = x_lds + 2 * INF;              // [2 buf][128]
    float* pre_lds = inp_lds + 2 * HID;            // [2 buf][128]

    const int tid = threadIdx.x;
    const int b   = blockIdx.x;

    // ---- stage Wrec transposed (all threads); stage1 wave stages x(0),x(1)
    for (int idx = tid; idx < HID * HID; idx += 256)
        Wrec_T[idx] = Wrec[(idx & (HID - 1)) * HID + (idx >> 7)];
    if (tid >= 128 && tid < 192) {
        int l = tid - 128;
        x_lds[0 * INF + l] = x[(size_t)(0 * BATCH + b) * INF + l];
        x_lds[1 * INF + l] = x[(size_t)(1 * BATCH + b) * INF + l];
    }
    __syncthreads();

    if (tid < 128) {
        // ================= STAGE2 role: pre = inp @ cWi.T =================
        const int h = tid;
        const float4* cwr = (const float4*)(cWi + h * HID);
        #define DECL_C(q) float4 c##q = cwr[q];
        FOR32(DECL_C)
        #undef DECL_C

        BARRIER();   // P1 (stage1 computes inp(0))

        // P2: pre(0) from inp_lds[0]
        {
            const float4* ir4 = (const float4*)(inp_lds + 0 * HID);
            float p = 0.f;
            #define S2(q) { float4 i4 = ir4[q]; \
                p = fmaf(i4.x, c##q.x, p); p = fmaf(i4.y, c##q.y, p); \
                p = fmaf(i4.z, c##q.z, p); p = fmaf(i4.w, c##q.w, p); }
            FOR32(S2)
            pre_lds[0 * HID + h] = p;
            BARRIER();

            for (int i = 0; i < T_STEPS; ++i) {
                const int nbuf = (i & 1) ^ 1;
                const float4* ir = (const float4*)(inp_lds + nbuf * HID); // inp(i+1)
                float pp = 0.f;
                #undef S2
                #define S2(q) { float4 i4 = ir[q]; \
                    pp = fmaf(i4.x, c##q.x, pp); pp = fmaf(i4.y, c##q.y, pp); \
                    pp = fmaf(i4.z, c##q.z, pp); pp = fmaf(i4.w, c##q.w, pp); }
                FOR32(S2)
                #undef S2
                pre_lds[nbuf * HID + h] = pp;                             // pre(i+1)
                BARRIER();
            }
        }
    } else if (tid < 192) {
        // ================= STAGE1 role: inp = x @ W_in.T (2 outputs/lane) =================
        const int l = tid - 128;
        const float4* wra = (const float4*)(W_in + l * INF);
        const float4* wrb = (const float4*)(W_in + (l + 64) * INF);
        #define DECL_AB(q) float4 a##q = wra[q]; float4 b##q = wrb[q];
        FOR16(DECL_AB)
        #undef DECL_AB

        #define S1(q) { float4 x4 = xr4[q]; \
            sa = fmaf(x4.x, a##q.x, sa); sa = fmaf(x4.y, a##q.y, sa); \
            sa = fmaf(x4.z, a##q.z, sa); sa = fmaf(x4.w, a##q.w, sa); \
            sb = fmaf(x4.x, b##q.x, sb); sb = fmaf(x4.y, b##q.y, sb); \
            sb = fmaf(x4.z, b##q.z, sb); sb = fmaf(x4.w, b##q.w, sb); }

        // P1: inp(0) from xbuf0
        {
            const float4* xr4 = (const float4*)(x_lds + 0 * INF);
            float sa = 0.f, sb = 0.f;
            FOR16(S1)
            inp_lds[0 * HID + l] = sa;
            inp_lds[0 * HID + 64 + l] = sb;
        }
        BARRIER();

        // P2: inp(1) from xbuf1; restage xbuf0 <- x(2); issue x(3)
        float xnext;
        {
            const float4* xr4 = (const float4*)(x_lds + 1 * INF);
            float sa = 0.f, sb = 0.f;
            FOR16(S1)
            inp_lds[1 * HID + l] = sa;
            inp_lds[1 * HID + 64 + l] = sb;
            x_lds[0 * INF + l] = x[(size_t)(2 * BATCH + b) * INF + l];
            xnext = x[(size_t)(3 * BATCH + b) * INF + l];
        }
        BARRIER();

        for (int i = 0; i < T_STEPS; ++i) {
            const int buf  = i & 1;
            const int nbuf = buf ^ 1;
            // x handoff: ds_write x(i+3); issue load x(i+4) (in flight across barrier)
            x_lds[nbuf * INF + l] = xnext;
            int tn = (i + 4 < T_STEPS) ? i + 4 : T_STEPS - 1;
            xnext = x[((size_t)tn * BATCH + b) * INF + l];
            // inp(i+2) from xbuf[buf] = x(i+2)
            const float4* xr4 = (const float4*)(x_lds + buf * INF);
            float sa = 0.f, sb = 0.f;
            FOR16(S1)
            inp_lds[buf * HID + l] = sa;
            inp_lds[buf * HID + 64 + l] = sb;
            BARRIER();
        }
        #undef S1
    } else {
        // ================= REC role: rec scan + LIF, 2 neurons/lane =================
        const int l  = tid - 192;
        const int h0 = 2 * l, h1 = 2 * l + 1;

        const double vth0  = (double)v_th[h0],    vth1  = (double)v_th[h1];
        const double vleak = (double)v_leak1[0];
        const double vrs0  = (double)v_reset[h0], vrs1  = (double)v_reset[h1];
        const double dtm0  = 0.001 * (double)tau_mem[h0];
        const double dtm1  = 0.001 * (double)tau_mem[h1];
        const double dts0  = 0.001 * (double)tau_syn[h0];
        const double dts1  = 0.001 * (double)tau_syn[h1];

        double v0 = 0.0, v1 = 0.0, c0 = 0.0, c1 = 0.0;
        int cnt0 = 0, cnt1 = 0;
        unsigned long long me = 0ull, mo = 0ull;   // masks z(i-1): even / odd neurons

        BARRIER();   // P1
        BARRIER();   // P2

        for (int i = 0; i < T_STEPS; ++i) {
            const int buf = i & 1;
            // pre(i) pair (adjacent f32) — issue early
            float2 pp = *(const float2*)(pre_lds + buf * HID + h0);

            // scan: rec = sum over spiking j of Wrec_T[j][h]  (f64-exact, any order)
            double s00 = 0.0, s01 = 0.0, s10 = 0.0, s11 = 0.0;
            {
                unsigned long long A = me, Bm = mo;
                while (A | Bm) {
                    float2 w0 = make_float2(0.f, 0.f), w1 = w0, w2 = w0, w3 = w0,
                           w4 = w0, w5 = w0, w6 = w0, w7 = w0;
                    if (A)  { int j = __builtin_ctzll(A);  A  &= A - 1;  w0 = *(const float2*)(Wrec_T + (2 * j) * HID + h0); }
                    if (A)  { int j = __builtin_ctzll(A);  A  &= A - 1;  w1 = *(const float2*)(Wrec_T + (2 * j) * HID + h0); }
                    if (A)  { int j = __builtin_ctzll(A);  A  &= A - 1;  w2 = *(const float2*)(Wrec_T + (2 * j) * HID + h0); }
                    if (A)  { int j = __builtin_ctzll(A);  A  &= A - 1;  w3 = *(const float2*)(Wrec_T + (2 * j) * HID + h0); }
                    if (Bm) { int j = __builtin_ctzll(Bm); Bm &= Bm - 1; w4 = *(const float2*)(Wrec_T + (2 * j + 1) * HID + h0); }
                    if (Bm) { int j = __builtin_ctzll(Bm); Bm &= Bm - 1; w5 = *(const float2*)(Wrec_T + (2 * j + 1) * HID + h0); }
                    if (Bm) { int j = __builtin_ctzll(Bm); Bm &= Bm - 1; w6 = *(const float2*)(Wrec_T + (2 * j + 1) * HID + h0); }
                    if (Bm) { int j = __builtin_ctzll(Bm); Bm &= Bm - 1; w7 = *(const float2*)(Wrec_T + (2 * j + 1) * HID + h0); }
                    s00 += (double)w0.x; s10 += (double)w0.y;
                    s01 += (double)w1.x; s11 += (double)w1.y;
                    s00 += (double)w2.x; s10 += (double)w2.y;
                    s01 += (double)w3.x; s11 += (double)w3.y;
                    s00 += (double)w4.x; s10 += (double)w4.y;
                    s01 += (double)w5.x; s11 += (double)w5.y;
                    s00 += (double)w6.x; s10 += (double)w6.y;
                    s01 += (double)w7.x; s11 += (double)w7.y;
                }
            }
            double rec0 = s00 + s01;
            double rec1 = s10 + s11;

            // LIF (float64, np op order, no contraction)
            double vd0 = v0 + dtm0 * ((vleak - v0) + c0);
            double id0 = c0 - dts0 * c0;
            bool   z0  = (vd0 - vth0) > 0.0;
            v0 = z0 ? vrs0 : vd0;
            c0 = (id0 + (double)pp.x) + rec0;
            cnt0 += z0 ? 1 : 0;

            double vd1 = v1 + dtm1 * ((vleak - v1) + c1);
            double id1 = c1 - dts1 * c1;
            bool   z1  = (vd1 - vth1) > 0.0;
            v1 = z1 ? vrs1 : vd1;
            c1 = (id1 + (double)pp.y) + rec1;
            cnt1 += z1 ? 1 : 0;

            me = __ballot(z0);   // masks for step i+1, stay in-wave
            mo = __ballot(z1);
            BARRIER();
        }

        // park counts for epilogue
        pre_lds[h0] = (float)cnt0;   // counts <= 1024: exact in f32
        pre_lds[h1] = (float)cnt1;
    }

    __syncthreads();

    // ---- epilogue: z_sum[b] = (sum_t z)@W_out.T + T*b_out ; global spike count
    const float* cnt_lds = pre_lds;
    if (tid < OUTF) {
        double sAcc = 0.0;
        for (int hh = 0; hh < HID; ++hh)
            sAcc += (double)cnt_lds[hh] * (double)W_out[tid * HID + hh];
        out[(size_t)b * OUTF + tid] = (float)(sAcc + 1024.0 * (double)b_out[tid]);
    }
    if (tid == 0) {
        unsigned int tot = 0;
        for (int k2 = 0; k2 < HID; ++k2) tot += (unsigned int)cnt_lds[k2];
        atomicAdd(counter, tot);
    }
}

__global__ void finalize_kernel(float* __restrict__ out)
{
    unsigned int c = ((const unsigned int*)out)[BATCH * OUTF];
    out[BATCH * OUTF] = (float)c * 0x1p-26f;   // / (1024*512*128), exact pow2
}

extern "C" void kernel_launch(void* const* d_in, const int* in_sizes, int n_in,
                              void* d_out, int out_size, void* d_ws, size_t ws_size,
                              hipStream_t stream) {
    (void)in_sizes; (void)n_in; (void)d_ws; (void)ws_size; (void)out_size;

    const float* x       = (const float*)d_in[0];
    const float* W_in    = (const float*)d_in[1];
    const float* cWi     = (const float*)d_in[2];
    const float* cWr     = (const float*)d_in[3];
    const float* W_out   = (const float*)d_in[4];
    const float* b_out   = (const float*)d_in[5];
    // d_in[6] = alpha (unused in forward)
    const float* v_th    = (const float*)d_in[7];
    const float* v_leak  = (const float*)d_in[8];
    const float* v_reset = (const float*)d_in[9];
    const float* tau_mem = (const float*)d_in[10];
    const float* tau_syn = (const float*)d_in[11];
    float* out = (float*)d_out;
    unsigned int* counter = (unsigned int*)out + BATCH * OUTF;

    zero_kernel<<<1, 1, 0, stream>>>(counter);

    const size_t lds_bytes =
        (size_t)(HID * HID + 2 * INF + 2 * HID + 2 * HID) * sizeof(float);
    snn_seq<<<dim3(512), dim3(256), lds_bytes, stream>>>(
        x, W_in, cWi, cWr, W_out, b_out, v_th, v_leak, v_reset,
        tau_mem, tau_syn, out, counter);

    finalize_kernel<<<1, 1, 0, stream>>>(out);
}